// Round 9
// baseline (373.817 us; speedup 1.0000x reference)
//
#include <hip/hip_runtime.h>
#include <hip/hip_bf16.h>

#define HWsz 16384
#define Cdim 64
#define HIDd 128
#define NEXP 4
#define NBAT 16

typedef _Float16 h8 __attribute__((ext_vector_type(8)));
typedef _Float16 h4 __attribute__((ext_vector_type(4)));
typedef float f4 __attribute__((ext_vector_type(4)));

// d_ws layout (bytes)
#define OFF_W1F 0        // 4*128*64 f16   = 65536 B
#define OFF_W2F 65536    // 4*128*128 f16  = 131072 B
#define OFF_W3F 196608   // 4*64*128 f16   = 65536 B
#define OFF_B1F 262144   // 4*128 f32      = 2048 B
#define OFF_B2F 264192   // 4*128 f32      = 2048 B
#define OFF_B3F 266240   // 4*64 f32       = 1024 B
#define OFF_GAP 267264   // 16*64 f32      = 4096 B
#define OFF_GIDX 271360  // 16*2 int       = 128 B
#define OFF_GW  271488   // 16*2 f32       = 128 B

// ---------------- prep: BN-fold/f16-cast + global average pool ----------------
// (R6 lesson: NO atomics here. Plain stores.)
__global__ void prep_k(const float* __restrict__ x, float* __restrict__ gap,
                       const float* __restrict__ W1, const float* __restrict__ b1,
                       const float* __restrict__ g1, const float* __restrict__ be1,
                       const float* __restrict__ m1, const float* __restrict__ v1,
                       const float* __restrict__ W2, const float* __restrict__ b2,
                       const float* __restrict__ g2, const float* __restrict__ be2,
                       const float* __restrict__ m2, const float* __restrict__ v2,
                       const float* __restrict__ W3, const float* __restrict__ b3,
                       _Float16* __restrict__ W1f, _Float16* __restrict__ W2f,
                       _Float16* __restrict__ W3f,
                       float* __restrict__ b1f, float* __restrict__ b2f,
                       float* __restrict__ b3f)
{
  const int t = threadIdx.x;             // 256
  if (blockIdx.x < 1024) {
    // ---- global average pool over one (b,c) row — 16 loads in flight
    const int bc = blockIdx.x;
    const float4* p4 = (const float4*)(x + (size_t)bc * HWsz);
    float s0 = 0.f, s1 = 0.f, s2 = 0.f, s3 = 0.f;
#pragma unroll
    for (int i = t; i < 4096; i += 1024) {
      const float4 a = p4[i], b4 = p4[i + 256], c4 = p4[i + 512], d4 = p4[i + 768];
      s0 += a.x + a.y + a.z + a.w;
      s1 += b4.x + b4.y + b4.z + b4.w;
      s2 += c4.x + c4.y + c4.z + c4.w;
      s3 += d4.x + d4.y + d4.z + d4.w;
    }
    float s = s0 + s1 + s2 + s3;
    for (int off = 32; off; off >>= 1) s += __shfl_down(s, off, 64);
    __shared__ float red[4];
    if ((t & 63) == 0) red[t >> 6] = s;
    __syncthreads();
    if (t == 0) gap[bc] = (red[0] + red[1] + red[2] + red[3]) * (1.0f / HWsz);
  } else {
    // ---- BN fold + f16 cast
    const int i = (blockIdx.x - 1024) * 256 + t;
    if (i < 32768) {                       // W1 [e][o][c], eo = i/64
      const int eo = i >> 6;
      const float inv = g1[eo] * rsqrtf(v1[eo] + 1e-5f);
      W1f[i] = (_Float16)(W1[i] * inv);
    } else if (i < 98304) {                // W2 [e][o][i], eo = j/128
      const int j = i - 32768;
      const int eo = j >> 7;
      const float inv = g2[eo] * rsqrtf(v2[eo] + 1e-5f);
      W2f[j] = (_Float16)(W2[j] * inv);
    } else if (i < 131072) {               // W3 (no BN)
      const int k = i - 98304;
      W3f[k] = (_Float16)W3[k];
    } else if (i < 131584) {               // b1'
      const int l = i - 131072;
      const float inv = g1[l] * rsqrtf(v1[l] + 1e-5f);
      b1f[l] = b1[l] * inv + be1[l] - m1[l] * inv;
    } else if (i < 132096) {               // b2'
      const int l = i - 131584;
      const float inv = g2[l] * rsqrtf(v2[l] + 1e-5f);
      b2f[l] = b2[l] * inv + be2[l] - m2[l] * inv;
    } else if (i < 132352) {               // b3'
      b3f[i - 132096] = b3[i - 132096];
    }
  }
}

// ---------------- gate: softmax + top2 + aux loss ----------------
__global__ void gate_k(const float* __restrict__ gap, const float* __restrict__ gwt,
                       const float* __restrict__ gb, int* __restrict__ gidx,
                       float* __restrict__ gwo, float* __restrict__ aux)
{
  const int t = threadIdx.x;  // 64 threads, one wave
  __shared__ float logits[NBAT][NEXP];
  __shared__ float gated[NBAT][NEXP];
  {
    const int b = t >> 2, e = t & 3;
    float s = gb[e];
    for (int c = 0; c < Cdim; c++) s += gap[b * Cdim + c] * gwt[e * Cdim + c];
    logits[b][e] = s;
  }
  __syncthreads();
  if (t < NBAT) {
    const int b = t;
    float p[NEXP];
    float mx = logits[b][0];
    for (int e = 1; e < NEXP; e++) mx = fmaxf(mx, logits[b][e]);
    float sum = 0.f;
    for (int e = 0; e < NEXP; e++) { p[e] = expf(logits[b][e] - mx); sum += p[e]; }
    for (int e = 0; e < NEXP; e++) p[e] /= sum;
    int i0 = 0;
    for (int e = 1; e < NEXP; e++) if (p[e] > p[i0]) i0 = e;   // ties -> lower idx
    int i1 = (i0 == 0) ? 1 : 0;
    for (int e = 0; e < NEXP; e++) if (e != i0 && p[e] > p[i1]) i1 = e;
    const float s2 = p[i0] + p[i1] + 1e-8f;
    const float w0 = p[i0] / s2, w1 = p[i1] / s2;
    gidx[2 * b] = i0; gidx[2 * b + 1] = i1;
    gwo[2 * b] = w0;  gwo[2 * b + 1] = w1;
    for (int e = 0; e < NEXP; e++)
      gated[b][e] = (e == i0) ? w0 : ((e == i1) ? w1 : 0.f);
  }
  __syncthreads();
  if (t == 0) {
    float imp[NEXP] = {0.f, 0.f, 0.f, 0.f};
    for (int b = 0; b < NBAT; b++)
      for (int e = 0; e < NEXP; e++) imp[e] += gated[b][e];
    float mean = 0.f;
    for (int e = 0; e < NEXP; e++) mean += imp[e];
    mean *= 0.25f;
    float var = 0.f;
    for (int e = 0; e < NEXP; e++) { const float d = imp[e] - mean; var += d * d; }
    var *= 0.25f;
    aux[0] = var / (mean * mean + 1e-10f);
  }
}

// ---------------- fused top-2 expert MLP ----------------
// v9: occupancy via exact LDS budget. 64-pos blocks (grid 4096), slot-serial,
// 3 phases/slot. LDS = Xs 8K + H1 16K + H2 16K = 40960 B EXACTLY -> 4 blocks/CU
// (163840 = 160 KB exactly). Biases read from global (L2-cached broadcast
// loads) instead of LDS staging. __launch_bounds__(256,4): caps VGPR at 128
// under BOTH documented interpretations of the 2nd arg (4 waves/EU -> 2048/16;
// 4 blocks/CU -> 2048/16); natural demand at this tile ~110 -> no spill
// (R5/R8 lesson: never cap below demand). Target: 16 waves/CU, 2x the TLP of
// v4/v6's 8, on the same proven phase/swizzle structure.
__global__ __launch_bounds__(256, 4)
void moe_main_k(const float* __restrict__ x, float* __restrict__ out,
                const _Float16* __restrict__ W1f, const _Float16* __restrict__ W2f,
                const _Float16* __restrict__ W3f,
                const float* __restrict__ b1f, const float* __restrict__ b2f,
                const float* __restrict__ b3f,
                const int* __restrict__ gidx, const float* __restrict__ gwv)
{
  // rows swizzled: byte ^= (row&7)<<4  (bijective per 8-row stripe)
  __shared__ __align__(16) char smem[40960];
  _Float16* Xs = (_Float16*)smem;            // [64][64] h16, rows 128 B
  _Float16* H1 = (_Float16*)(smem + 8192);   // [64][128] h16, rows 256 B
  _Float16* H2 = (_Float16*)(smem + 24576);  // [64][128] h16

  const int bx = blockIdx.x;
  const int b  = bx >> 8;            // sample
  const int n0 = (bx & 255) << 6;    // 64-position tile base
  const int t  = threadIdx.x;
  const int w  = t >> 6;
  const int lane = t & 63;
  const int ln = lane & 15;   // MFMA n / m lane index
  const int q  = lane >> 4;   // quad
  const int mh = w >> 1;      // out-channel half
  const int nh = w & 1;       // position half

  const int   ea0 = gidx[2 * b], ea1 = gidx[2 * b + 1];
  const float wa0 = gwv[2 * b],  wa1 = gwv[2 * b + 1];

  // ---- stage X tile (lane = position: 256B coalesced segments, h4 LDS writes)
  {
    const int pos = t & 63;
    const int cb  = (t >> 6) << 4;   // 16-channel group base per wave
    const int sw  = (pos & 7) << 4;
    const float* xc = x + (size_t)b * (Cdim * HWsz) + n0 + pos;
#pragma unroll
    for (int j = 0; j < 4; j++) {
      const int c = cb + (j << 2);
      const float v0 = xc[(size_t)(c + 0) * HWsz];
      const float v1 = xc[(size_t)(c + 1) * HWsz];
      const float v2 = xc[(size_t)(c + 2) * HWsz];
      const float v3 = xc[(size_t)(c + 3) * HWsz];
      h4 hv; hv[0] = (_Float16)v0; hv[1] = (_Float16)v1;
             hv[2] = (_Float16)v2; hv[3] = (_Float16)v3;
      *(h4*)((char*)Xs + pos * 128 + ((c << 1) ^ sw)) = hv;
    }
  }

  f4 oacc[2][2];   // [mi][ni]
#pragma unroll
  for (int i = 0; i < 2; i++)
#pragma unroll
    for (int j = 0; j < 2; j++)
      oacc[i][j] = f4{0.f, 0.f, 0.f, 0.f};

  __syncthreads();   // X staged

#pragma unroll 1
  for (int slot = 0; slot < 2; slot++) {
    const int   e  = slot ? ea1 : ea0;
    const float we = slot ? wa1 : wa0;
    const _Float16* w1 = W1f + e * (HIDd * Cdim);
    const _Float16* w2 = W2f + e * (HIDd * HIDd);
    const _Float16* w3 = W3f + e * (Cdim * HIDd);
    const float* bb1 = b1f + e * HIDd;
    const float* bb2 = b2f + e * HIDd;
    const float* bb3 = b3f + e * Cdim;

    // ---- P1: L1, Xs -> H1 (K=64)
#pragma unroll
    for (int ni = 0; ni < 2; ni++) {
      const int nrow = ((nh << 1) + ni) * 16 + ln;
      const int sw = (nrow & 7) << 4;
      const h8 bf0 = *(const h8*)((const char*)Xs + nrow * 128 + ((q * 16) ^ sw));
      const h8 bf1 = *(const h8*)((const char*)Xs + nrow * 128 + ((64 + q * 16) ^ sw));
      __builtin_amdgcn_s_setprio(1);
#pragma unroll
      for (int mi = 0; mi < 4; mi++) {
        const int m0 = (((mh << 2) + mi) << 4);
        const _Float16* p1 = w1 + (m0 + ln) * Cdim + q * 8;
        f4 acc = {0.f, 0.f, 0.f, 0.f};
        acc = __builtin_amdgcn_mfma_f32_16x16x32_f16(*(const h8*)(p1), bf0, acc, 0, 0, 0);
        acc = __builtin_amdgcn_mfma_f32_16x16x32_f16(*(const h8*)(p1 + 32), bf1, acc, 0, 0, 0);
        const f4 bv = *(const f4*)(bb1 + m0 + q * 4);
        h4 hv;
#pragma unroll
        for (int r = 0; r < 4; r++) hv[r] = (_Float16)fmaxf(acc[r] + bv[r], 0.f);
        *(h4*)((char*)H1 + nrow * 256 + (((m0 << 1) + (q << 3)) ^ sw)) = hv;
      }
      __builtin_amdgcn_s_setprio(0);
    }
    __syncthreads();

    // ---- P2: L2, H1 -> H2 (K=128)
#pragma unroll
    for (int ni = 0; ni < 2; ni++) {
      const int nrow = ((nh << 1) + ni) * 16 + ln;
      const int sw = (nrow & 7) << 4;
      h8 bf[4];
#pragma unroll
      for (int ks = 0; ks < 4; ks++)
        bf[ks] = *(const h8*)((const char*)H1 + nrow * 256 + (((ks << 6) + (q << 4)) ^ sw));
      __builtin_amdgcn_s_setprio(1);
#pragma unroll
      for (int mi = 0; mi < 4; mi++) {
        const int m0 = (((mh << 2) + mi) << 4);
        const _Float16* p2 = w2 + (m0 + ln) * HIDd + q * 8;
        f4 acc = {0.f, 0.f, 0.f, 0.f};
#pragma unroll
        for (int ks = 0; ks < 4; ks++)
          acc = __builtin_amdgcn_mfma_f32_16x16x32_f16(*(const h8*)(p2 + ks * 32), bf[ks], acc, 0, 0, 0);
        const f4 bv = *(const f4*)(bb2 + m0 + q * 4);
        h4 hv;
#pragma unroll
        for (int r = 0; r < 4; r++) hv[r] = (_Float16)fmaxf(acc[r] + bv[r], 0.f);
        *(h4*)((char*)H2 + nrow * 256 + (((m0 << 1) + (q << 3)) ^ sw)) = hv;
      }
      __builtin_amdgcn_s_setprio(0);
    }
    __syncthreads();

    // ---- P3: L3, H2 -> oacc (M=64, K=128, weighted)
#pragma unroll
    for (int ni = 0; ni < 2; ni++) {
      const int nrow = ((nh << 1) + ni) * 16 + ln;
      const int sw = (nrow & 7) << 4;
      h8 bf[4];
#pragma unroll
      for (int ks = 0; ks < 4; ks++)
        bf[ks] = *(const h8*)((const char*)H2 + nrow * 256 + (((ks << 6) + (q << 4)) ^ sw));
      __builtin_amdgcn_s_setprio(1);
#pragma unroll
      for (int mi = 0; mi < 2; mi++) {
        const int m0 = (((mh << 1) + mi) << 4);
        const _Float16* p3 = w3 + (m0 + ln) * HIDd + q * 8;
        f4 acc = {0.f, 0.f, 0.f, 0.f};
#pragma unroll
        for (int ks = 0; ks < 4; ks++)
          acc = __builtin_amdgcn_mfma_f32_16x16x32_f16(*(const h8*)(p3 + ks * 32), bf[ks], acc, 0, 0, 0);
        const f4 bv = *(const f4*)(bb3 + m0 + q * 4);
#pragma unroll
        for (int r = 0; r < 4; r++) oacc[mi][ni][r] += we * (acc[r] + bv[r]);
      }
      __builtin_amdgcn_s_setprio(0);
    }
    __syncthreads();   // H2 WAR: slot1's P2 rewrites H2 after slot0's P3 reads
  }

  // ---- store output (fp32, nontemporal streaming)
#pragma unroll
  for (int mi = 0; mi < 2; mi++)
#pragma unroll
    for (int ni = 0; ni < 2; ni++) {
      const int c = ((mh << 1) + mi) * 16 + q * 4;
      const int n = n0 + ((nh << 1) + ni) * 16 + ln;
#pragma unroll
      for (int r = 0; r < 4; r++)
        __builtin_nontemporal_store(oacc[mi][ni][r],
                                    &out[((size_t)(b * Cdim + c + r)) * HWsz + n]);
    }
}

extern "C" void kernel_launch(void* const* d_in, const int* in_sizes, int n_in,
                              void* d_out, int out_size, void* d_ws, size_t ws_size,
                              hipStream_t stream)
{
  const float* x   = (const float*)d_in[0];
  const float* W1  = (const float*)d_in[1];
  const float* b1  = (const float*)d_in[2];
  const float* g1  = (const float*)d_in[3];
  const float* be1 = (const float*)d_in[4];
  const float* m1  = (const float*)d_in[5];
  const float* v1  = (const float*)d_in[6];
  const float* W2  = (const float*)d_in[7];
  const float* b2  = (const float*)d_in[8];
  const float* g2  = (const float*)d_in[9];
  const float* be2 = (const float*)d_in[10];
  const float* m2  = (const float*)d_in[11];
  const float* v2  = (const float*)d_in[12];
  const float* W3  = (const float*)d_in[13];
  const float* b3  = (const float*)d_in[14];
  const float* gwt = (const float*)d_in[15];
  const float* gb  = (const float*)d_in[16];

  char* ws = (char*)d_ws;
  _Float16* W1f = (_Float16*)(ws + OFF_W1F);
  _Float16* W2f = (_Float16*)(ws + OFF_W2F);
  _Float16* W3f = (_Float16*)(ws + OFF_W3F);
  float* b1f = (float*)(ws + OFF_B1F);
  float* b2f = (float*)(ws + OFF_B2F);
  float* b3f = (float*)(ws + OFF_B3F);
  float* gap = (float*)(ws + OFF_GAP);
  int*   gidx = (int*)(ws + OFF_GIDX);
  float* gwo = (float*)(ws + OFF_GW);

  float* out = (float*)d_out;
  float* aux = out + (size_t)NBAT * Cdim * HWsz;  // d_out[16777216]

  hipLaunchKernelGGL(prep_k, dim3(1542), dim3(256), 0, stream,
                     x, gap, W1, b1, g1, be1, m1, v1, W2, b2, g2, be2, m2, v2,
                     W3, b3, W1f, W2f, W3f, b1f, b2f, b3f);
  hipLaunchKernelGGL(gate_k, dim3(1), dim3(64), 0, stream, gap, gwt, gb, gidx, gwo, aux);
  hipLaunchKernelGGL(moe_main_k, dim3(4096), dim3(256), 0, stream,
                     x, out, W1f, W2f, W3f, b1f, b2f, b3f, gidx, gwo);
}

// Round 10
// 361.564 us; speedup vs baseline: 1.0339x; 1.0339x over previous
//
#include <hip/hip_runtime.h>
#include <hip/hip_bf16.h>

#define HWsz 16384
#define Cdim 64
#define HIDd 128
#define NEXP 4
#define NBAT 16

typedef _Float16 h8 __attribute__((ext_vector_type(8)));
typedef _Float16 h4 __attribute__((ext_vector_type(4)));
typedef float f4 __attribute__((ext_vector_type(4)));

// d_ws layout (bytes)
#define OFF_W1F 0        // 4*128*64 f16   = 65536 B
#define OFF_W2F 65536    // 4*128*128 f16  = 131072 B
#define OFF_W3F 196608   // 4*64*128 f16   = 65536 B
#define OFF_B1F 262144   // 4*128 f32      = 2048 B
#define OFF_B2F 264192   // 4*128 f32      = 2048 B
#define OFF_B3F 266240   // 4*64 f32       = 1024 B
#define OFF_GAP 267264   // 16*64 f32      = 4096 B
#define OFF_GIDX 271360  // 16*2 int       = 128 B
#define OFF_GW  271488   // 16*2 f32       = 128 B

// ---------------- prep: BN-fold/f16-cast + global average pool ----------------
// (R6 lesson: NO atomics here. Plain stores.)
__global__ void prep_k(const float* __restrict__ x, float* __restrict__ gap,
                       const float* __restrict__ W1, const float* __restrict__ b1,
                       const float* __restrict__ g1, const float* __restrict__ be1,
                       const float* __restrict__ m1, const float* __restrict__ v1,
                       const float* __restrict__ W2, const float* __restrict__ b2,
                       const float* __restrict__ g2, const float* __restrict__ be2,
                       const float* __restrict__ m2, const float* __restrict__ v2,
                       const float* __restrict__ W3, const float* __restrict__ b3,
                       _Float16* __restrict__ W1f, _Float16* __restrict__ W2f,
                       _Float16* __restrict__ W3f,
                       float* __restrict__ b1f, float* __restrict__ b2f,
                       float* __restrict__ b3f)
{
  const int t = threadIdx.x;             // 256
  if (blockIdx.x < 1024) {
    // ---- global average pool over one (b,c) row — 16 loads in flight
    const int bc = blockIdx.x;
    const float4* p4 = (const float4*)(x + (size_t)bc * HWsz);
    float s0 = 0.f, s1 = 0.f, s2 = 0.f, s3 = 0.f;
#pragma unroll
    for (int i = t; i < 4096; i += 1024) {
      const float4 a = p4[i], b4 = p4[i + 256], c4 = p4[i + 512], d4 = p4[i + 768];
      s0 += a.x + a.y + a.z + a.w;
      s1 += b4.x + b4.y + b4.z + b4.w;
      s2 += c4.x + c4.y + c4.z + c4.w;
      s3 += d4.x + d4.y + d4.z + d4.w;
    }
    float s = s0 + s1 + s2 + s3;
    for (int off = 32; off; off >>= 1) s += __shfl_down(s, off, 64);
    __shared__ float red[4];
    if ((t & 63) == 0) red[t >> 6] = s;
    __syncthreads();
    if (t == 0) gap[bc] = (red[0] + red[1] + red[2] + red[3]) * (1.0f / HWsz);
  } else {
    // ---- BN fold + f16 cast
    const int i = (blockIdx.x - 1024) * 256 + t;
    if (i < 32768) {                       // W1 [e][o][c], eo = i/64
      const int eo = i >> 6;
      const float inv = g1[eo] * rsqrtf(v1[eo] + 1e-5f);
      W1f[i] = (_Float16)(W1[i] * inv);
    } else if (i < 98304) {                // W2 [e][o][i], eo = j/128
      const int j = i - 32768;
      const int eo = j >> 7;
      const float inv = g2[eo] * rsqrtf(v2[eo] + 1e-5f);
      W2f[j] = (_Float16)(W2[j] * inv);
    } else if (i < 131072) {               // W3 (no BN)
      const int k = i - 98304;
      W3f[k] = (_Float16)W3[k];
    } else if (i < 131584) {               // b1'
      const int l = i - 131072;
      const float inv = g1[l] * rsqrtf(v1[l] + 1e-5f);
      b1f[l] = b1[l] * inv + be1[l] - m1[l] * inv;
    } else if (i < 132096) {               // b2'
      const int l = i - 131584;
      const float inv = g2[l] * rsqrtf(v2[l] + 1e-5f);
      b2f[l] = b2[l] * inv + be2[l] - m2[l] * inv;
    } else if (i < 132352) {               // b3'
      b3f[i - 132096] = b3[i - 132096];
    }
  }
}

// ---------------- gate: softmax + top2 + aux loss ----------------
__global__ void gate_k(const float* __restrict__ gap, const float* __restrict__ gwt,
                       const float* __restrict__ gb, int* __restrict__ gidx,
                       float* __restrict__ gwo, float* __restrict__ aux)
{
  const int t = threadIdx.x;  // 64 threads, one wave
  __shared__ float logits[NBAT][NEXP];
  __shared__ float gated[NBAT][NEXP];
  {
    const int b = t >> 2, e = t & 3;
    float s = gb[e];
    for (int c = 0; c < Cdim; c++) s += gap[b * Cdim + c] * gwt[e * Cdim + c];
    logits[b][e] = s;
  }
  __syncthreads();
  if (t < NBAT) {
    const int b = t;
    float p[NEXP];
    float mx = logits[b][0];
    for (int e = 1; e < NEXP; e++) mx = fmaxf(mx, logits[b][e]);
    float sum = 0.f;
    for (int e = 0; e < NEXP; e++) { p[e] = expf(logits[b][e] - mx); sum += p[e]; }
    for (int e = 0; e < NEXP; e++) p[e] /= sum;
    int i0 = 0;
    for (int e = 1; e < NEXP; e++) if (p[e] > p[i0]) i0 = e;   // ties -> lower idx
    int i1 = (i0 == 0) ? 1 : 0;
    for (int e = 0; e < NEXP; e++) if (e != i0 && p[e] > p[i1]) i1 = e;
    const float s2 = p[i0] + p[i1] + 1e-8f;
    const float w0 = p[i0] / s2, w1 = p[i1] / s2;
    gidx[2 * b] = i0; gidx[2 * b + 1] = i1;
    gwo[2 * b] = w0;  gwo[2 * b + 1] = w1;
    for (int e = 0; e < NEXP; e++)
      gated[b][e] = (e == i0) ? w0 : ((e == i1) ? w1 : 0.f);
  }
  __syncthreads();
  if (t == 0) {
    float imp[NEXP] = {0.f, 0.f, 0.f, 0.f};
    for (int b = 0; b < NBAT; b++)
      for (int e = 0; e < NEXP; e++) imp[e] += gated[b][e];
    float mean = 0.f;
    for (int e = 0; e < NEXP; e++) mean += imp[e];
    mean *= 0.25f;
    float var = 0.f;
    for (int e = 0; e < NEXP; e++) { const float d = imp[e] - mean; var += d * d; }
    var *= 0.25f;
    aux[0] = var / (mean * mean + 1e-10f);
  }
}

// ---------------- fused top-2 expert MLP ----------------
// v10 = v9 structure with __launch_bounds__(256,3).
// Empirical law from R4/R5/R6/R8/R9: VGPR cap = 256/arg2, blocks/CU = arg2.
//   (256,2) -> 128 regs, 2 blocks, no spill, 103 µs   [v4/v6]
//   (256,4) ->  64 regs, 4 blocks, SPILL, 251 µs      [v9]
//   (256,3) ->  84 regs, 3 blocks, ??? <- this experiment
// v9's inline per-mi weight loads are the leanest-register form (~85-100
// natural demand, vs 124-128 for the batched/pinned forms) — 84 should fit
// with at most marginal spill (R5's failure at arg2=3 was caused by 64
// PINNED weight regs, absent here). LDS stays 40960 B (not binding at 3).
__global__ __launch_bounds__(256, 3)
void moe_main_k(const float* __restrict__ x, float* __restrict__ out,
                const _Float16* __restrict__ W1f, const _Float16* __restrict__ W2f,
                const _Float16* __restrict__ W3f,
                const float* __restrict__ b1f, const float* __restrict__ b2f,
                const float* __restrict__ b3f,
                const int* __restrict__ gidx, const float* __restrict__ gwv)
{
  // rows swizzled: byte ^= (row&7)<<4  (bijective per 8-row stripe)
  __shared__ __align__(16) char smem[40960];
  _Float16* Xs = (_Float16*)smem;            // [64][64] h16, rows 128 B
  _Float16* H1 = (_Float16*)(smem + 8192);   // [64][128] h16, rows 256 B
  _Float16* H2 = (_Float16*)(smem + 24576);  // [64][128] h16

  const int bx = blockIdx.x;
  const int b  = bx >> 8;            // sample
  const int n0 = (bx & 255) << 6;    // 64-position tile base
  const int t  = threadIdx.x;
  const int w  = t >> 6;
  const int lane = t & 63;
  const int ln = lane & 15;   // MFMA n / m lane index
  const int q  = lane >> 4;   // quad
  const int mh = w >> 1;      // out-channel half
  const int nh = w & 1;       // position half

  const int   ea0 = gidx[2 * b], ea1 = gidx[2 * b + 1];
  const float wa0 = gwv[2 * b],  wa1 = gwv[2 * b + 1];

  // ---- stage X tile (lane = position: 256B coalesced segments, h4 LDS writes)
  {
    const int pos = t & 63;
    const int cb  = (t >> 6) << 4;   // 16-channel group base per wave
    const int sw  = (pos & 7) << 4;
    const float* xc = x + (size_t)b * (Cdim * HWsz) + n0 + pos;
#pragma unroll
    for (int j = 0; j < 4; j++) {
      const int c = cb + (j << 2);
      const float v0 = xc[(size_t)(c + 0) * HWsz];
      const float v1 = xc[(size_t)(c + 1) * HWsz];
      const float v2 = xc[(size_t)(c + 2) * HWsz];
      const float v3 = xc[(size_t)(c + 3) * HWsz];
      h4 hv; hv[0] = (_Float16)v0; hv[1] = (_Float16)v1;
             hv[2] = (_Float16)v2; hv[3] = (_Float16)v3;
      *(h4*)((char*)Xs + pos * 128 + ((c << 1) ^ sw)) = hv;
    }
  }

  f4 oacc[2][2];   // [mi][ni]
#pragma unroll
  for (int i = 0; i < 2; i++)
#pragma unroll
    for (int j = 0; j < 2; j++)
      oacc[i][j] = f4{0.f, 0.f, 0.f, 0.f};

  __syncthreads();   // X staged

#pragma unroll 1
  for (int slot = 0; slot < 2; slot++) {
    const int   e  = slot ? ea1 : ea0;
    const float we = slot ? wa1 : wa0;
    const _Float16* w1 = W1f + e * (HIDd * Cdim);
    const _Float16* w2 = W2f + e * (HIDd * HIDd);
    const _Float16* w3 = W3f + e * (Cdim * HIDd);
    const float* bb1 = b1f + e * HIDd;
    const float* bb2 = b2f + e * HIDd;
    const float* bb3 = b3f + e * Cdim;

    // ---- P1: L1, Xs -> H1 (K=64)
#pragma unroll
    for (int ni = 0; ni < 2; ni++) {
      const int nrow = ((nh << 1) + ni) * 16 + ln;
      const int sw = (nrow & 7) << 4;
      const h8 bf0 = *(const h8*)((const char*)Xs + nrow * 128 + ((q * 16) ^ sw));
      const h8 bf1 = *(const h8*)((const char*)Xs + nrow * 128 + ((64 + q * 16) ^ sw));
      __builtin_amdgcn_s_setprio(1);
#pragma unroll
      for (int mi = 0; mi < 4; mi++) {
        const int m0 = (((mh << 2) + mi) << 4);
        const _Float16* p1 = w1 + (m0 + ln) * Cdim + q * 8;
        f4 acc = {0.f, 0.f, 0.f, 0.f};
        acc = __builtin_amdgcn_mfma_f32_16x16x32_f16(*(const h8*)(p1), bf0, acc, 0, 0, 0);
        acc = __builtin_amdgcn_mfma_f32_16x16x32_f16(*(const h8*)(p1 + 32), bf1, acc, 0, 0, 0);
        const f4 bv = *(const f4*)(bb1 + m0 + q * 4);
        h4 hv;
#pragma unroll
        for (int r = 0; r < 4; r++) hv[r] = (_Float16)fmaxf(acc[r] + bv[r], 0.f);
        *(h4*)((char*)H1 + nrow * 256 + (((m0 << 1) + (q << 3)) ^ sw)) = hv;
      }
      __builtin_amdgcn_s_setprio(0);
    }
    __syncthreads();

    // ---- P2: L2, H1 -> H2 (K=128)
#pragma unroll
    for (int ni = 0; ni < 2; ni++) {
      const int nrow = ((nh << 1) + ni) * 16 + ln;
      const int sw = (nrow & 7) << 4;
      h8 bf[4];
#pragma unroll
      for (int ks = 0; ks < 4; ks++)
        bf[ks] = *(const h8*)((const char*)H1 + nrow * 256 + (((ks << 6) + (q << 4)) ^ sw));
      __builtin_amdgcn_s_setprio(1);
#pragma unroll
      for (int mi = 0; mi < 4; mi++) {
        const int m0 = (((mh << 2) + mi) << 4);
        const _Float16* p2 = w2 + (m0 + ln) * HIDd + q * 8;
        f4 acc = {0.f, 0.f, 0.f, 0.f};
#pragma unroll
        for (int ks = 0; ks < 4; ks++)
          acc = __builtin_amdgcn_mfma_f32_16x16x32_f16(*(const h8*)(p2 + ks * 32), bf[ks], acc, 0, 0, 0);
        const f4 bv = *(const f4*)(bb2 + m0 + q * 4);
        h4 hv;
#pragma unroll
        for (int r = 0; r < 4; r++) hv[r] = (_Float16)fmaxf(acc[r] + bv[r], 0.f);
        *(h4*)((char*)H2 + nrow * 256 + (((m0 << 1) + (q << 3)) ^ sw)) = hv;
      }
      __builtin_amdgcn_s_setprio(0);
    }
    __syncthreads();

    // ---- P3: L3, H2 -> oacc (M=64, K=128, weighted)
#pragma unroll
    for (int ni = 0; ni < 2; ni++) {
      const int nrow = ((nh << 1) + ni) * 16 + ln;
      const int sw = (nrow & 7) << 4;
      h8 bf[4];
#pragma unroll
      for (int ks = 0; ks < 4; ks++)
        bf[ks] = *(const h8*)((const char*)H2 + nrow * 256 + (((ks << 6) + (q << 4)) ^ sw));
      __builtin_amdgcn_s_setprio(1);
#pragma unroll
      for (int mi = 0; mi < 2; mi++) {
        const int m0 = (((mh << 1) + mi) << 4);
        const _Float16* p3 = w3 + (m0 + ln) * HIDd + q * 8;
        f4 acc = {0.f, 0.f, 0.f, 0.f};
#pragma unroll
        for (int ks = 0; ks < 4; ks++)
          acc = __builtin_amdgcn_mfma_f32_16x16x32_f16(*(const h8*)(p3 + ks * 32), bf[ks], acc, 0, 0, 0);
        const f4 bv = *(const f4*)(bb3 + m0 + q * 4);
#pragma unroll
        for (int r = 0; r < 4; r++) oacc[mi][ni][r] += we * (acc[r] + bv[r]);
      }
      __builtin_amdgcn_s_setprio(0);
    }
    __syncthreads();   // H2 WAR: slot1's P2 rewrites H2 after slot0's P3 reads
  }

  // ---- store output (fp32, nontemporal streaming)
#pragma unroll
  for (int mi = 0; mi < 2; mi++)
#pragma unroll
    for (int ni = 0; ni < 2; ni++) {
      const int c = ((mh << 1) + mi) * 16 + q * 4;
      const int n = n0 + ((nh << 1) + ni) * 16 + ln;
#pragma unroll
      for (int r = 0; r < 4; r++)
        __builtin_nontemporal_store(oacc[mi][ni][r],
                                    &out[((size_t)(b * Cdim + c + r)) * HWsz + n]);
    }
}

extern "C" void kernel_launch(void* const* d_in, const int* in_sizes, int n_in,
                              void* d_out, int out_size, void* d_ws, size_t ws_size,
                              hipStream_t stream)
{
  const float* x   = (const float*)d_in[0];
  const float* W1  = (const float*)d_in[1];
  const float* b1  = (const float*)d_in[2];
  const float* g1  = (const float*)d_in[3];
  const float* be1 = (const float*)d_in[4];
  const float* m1  = (const float*)d_in[5];
  const float* v1  = (const float*)d_in[6];
  const float* W2  = (const float*)d_in[7];
  const float* b2  = (const float*)d_in[8];
  const float* g2  = (const float*)d_in[9];
  const float* be2 = (const float*)d_in[10];
  const float* m2  = (const float*)d_in[11];
  const float* v2  = (const float*)d_in[12];
  const float* W3  = (const float*)d_in[13];
  const float* b3  = (const float*)d_in[14];
  const float* gwt = (const float*)d_in[15];
  const float* gb  = (const float*)d_in[16];

  char* ws = (char*)d_ws;
  _Float16* W1f = (_Float16*)(ws + OFF_W1F);
  _Float16* W2f = (_Float16*)(ws + OFF_W2F);
  _Float16* W3f = (_Float16*)(ws + OFF_W3F);
  float* b1f = (float*)(ws + OFF_B1F);
  float* b2f = (float*)(ws + OFF_B2F);
  float* b3f = (float*)(ws + OFF_B3F);
  float* gap = (float*)(ws + OFF_GAP);
  int*   gidx = (int*)(ws + OFF_GIDX);
  float* gwo = (float*)(ws + OFF_GW);

  float* out = (float*)d_out;
  float* aux = out + (size_t)NBAT * Cdim * HWsz;  // d_out[16777216]

  hipLaunchKernelGGL(prep_k, dim3(1542), dim3(256), 0, stream,
                     x, gap, W1, b1, g1, be1, m1, v1, W2, b2, g2, be2, m2, v2,
                     W3, b3, W1f, W2f, W3f, b1f, b2f, b3f);
  hipLaunchKernelGGL(gate_k, dim3(1), dim3(64), 0, stream, gap, gwt, gb, gidx, gwo, aux);
  hipLaunchKernelGGL(moe_main_k, dim3(4096), dim3(256), 0, stream,
                     x, out, W1f, W2f, W3f, b1f, b2f, b3f, gidx, gwo);
}

// Round 11
// 194.329 us; speedup vs baseline: 1.9236x; 1.8606x over previous
//
#include <hip/hip_runtime.h>
#include <hip/hip_bf16.h>

#define HWsz 16384
#define Cdim 64
#define HIDd 128
#define NEXP 4
#define NBAT 16

typedef _Float16 h8 __attribute__((ext_vector_type(8)));
typedef _Float16 h4 __attribute__((ext_vector_type(4)));
typedef float f4 __attribute__((ext_vector_type(4)));

// d_ws layout (bytes)
#define OFF_W1F 0        // 4*128*64 f16   = 65536 B
#define OFF_W2F 65536    // 4*128*128 f16  = 131072 B
#define OFF_W3F 196608   // 4*64*128 f16   = 65536 B
#define OFF_B1F 262144   // 4*128 f32      = 2048 B
#define OFF_B2F 264192   // 4*128 f32      = 2048 B
#define OFF_B3F 266240   // 4*64 f32       = 1024 B
#define OFF_GAP 267264   // 16*64 f32      = 4096 B
#define OFF_GIDX 271360  // 16*2 int       = 128 B
#define OFF_GW  271488   // 16*2 f32       = 128 B

// ---------------- prep: BN-fold/f16-cast + global average pool ----------------
// (R6 lesson: NO atomics here. Plain stores.)
__global__ void prep_k(const float* __restrict__ x, float* __restrict__ gap,
                       const float* __restrict__ W1, const float* __restrict__ b1,
                       const float* __restrict__ g1, const float* __restrict__ be1,
                       const float* __restrict__ m1, const float* __restrict__ v1,
                       const float* __restrict__ W2, const float* __restrict__ b2,
                       const float* __restrict__ g2, const float* __restrict__ be2,
                       const float* __restrict__ m2, const float* __restrict__ v2,
                       const float* __restrict__ W3, const float* __restrict__ b3,
                       _Float16* __restrict__ W1f, _Float16* __restrict__ W2f,
                       _Float16* __restrict__ W3f,
                       float* __restrict__ b1f, float* __restrict__ b2f,
                       float* __restrict__ b3f)
{
  const int t = threadIdx.x;             // 256
  if (blockIdx.x < 1024) {
    // ---- global average pool over one (b,c) row — 16 loads in flight
    const int bc = blockIdx.x;
    const float4* p4 = (const float4*)(x + (size_t)bc * HWsz);
    float s0 = 0.f, s1 = 0.f, s2 = 0.f, s3 = 0.f;
#pragma unroll
    for (int i = t; i < 4096; i += 1024) {
      const float4 a = p4[i], b4 = p4[i + 256], c4 = p4[i + 512], d4 = p4[i + 768];
      s0 += a.x + a.y + a.z + a.w;
      s1 += b4.x + b4.y + b4.z + b4.w;
      s2 += c4.x + c4.y + c4.z + c4.w;
      s3 += d4.x + d4.y + d4.z + d4.w;
    }
    float s = s0 + s1 + s2 + s3;
    for (int off = 32; off; off >>= 1) s += __shfl_down(s, off, 64);
    __shared__ float red[4];
    if ((t & 63) == 0) red[t >> 6] = s;
    __syncthreads();
    if (t == 0) gap[bc] = (red[0] + red[1] + red[2] + red[3]) * (1.0f / HWsz);
  } else {
    // ---- BN fold + f16 cast
    const int i = (blockIdx.x - 1024) * 256 + t;
    if (i < 32768) {                       // W1 [e][o][c], eo = i/64
      const int eo = i >> 6;
      const float inv = g1[eo] * rsqrtf(v1[eo] + 1e-5f);
      W1f[i] = (_Float16)(W1[i] * inv);
    } else if (i < 98304) {                // W2 [e][o][i], eo = j/128
      const int j = i - 32768;
      const int eo = j >> 7;
      const float inv = g2[eo] * rsqrtf(v2[eo] + 1e-5f);
      W2f[j] = (_Float16)(W2[j] * inv);
    } else if (i < 131072) {               // W3 (no BN)
      const int k = i - 98304;
      W3f[k] = (_Float16)W3[k];
    } else if (i < 131584) {               // b1'
      const int l = i - 131072;
      const float inv = g1[l] * rsqrtf(v1[l] + 1e-5f);
      b1f[l] = b1[l] * inv + be1[l] - m1[l] * inv;
    } else if (i < 132096) {               // b2'
      const int l = i - 131584;
      const float inv = g2[l] * rsqrtf(v2[l] + 1e-5f);
      b2f[l] = b2[l] * inv + be2[l] - m2[l] * inv;
    } else if (i < 132352) {               // b3'
      b3f[i - 132096] = b3[i - 132096];
    }
  }
}

// ---------------- gate: softmax + top2 + aux loss ----------------
__global__ void gate_k(const float* __restrict__ gap, const float* __restrict__ gwt,
                       const float* __restrict__ gb, int* __restrict__ gidx,
                       float* __restrict__ gwo, float* __restrict__ aux)
{
  const int t = threadIdx.x;  // 64 threads, one wave
  __shared__ float logits[NBAT][NEXP];
  __shared__ float gated[NBAT][NEXP];
  {
    const int b = t >> 2, e = t & 3;
    float s = gb[e];
    for (int c = 0; c < Cdim; c++) s += gap[b * Cdim + c] * gwt[e * Cdim + c];
    logits[b][e] = s;
  }
  __syncthreads();
  if (t < NBAT) {
    const int b = t;
    float p[NEXP];
    float mx = logits[b][0];
    for (int e = 1; e < NEXP; e++) mx = fmaxf(mx, logits[b][e]);
    float sum = 0.f;
    for (int e = 0; e < NEXP; e++) { p[e] = expf(logits[b][e] - mx); sum += p[e]; }
    for (int e = 0; e < NEXP; e++) p[e] /= sum;
    int i0 = 0;
    for (int e = 1; e < NEXP; e++) if (p[e] > p[i0]) i0 = e;   // ties -> lower idx
    int i1 = (i0 == 0) ? 1 : 0;
    for (int e = 0; e < NEXP; e++) if (e != i0 && p[e] > p[i1]) i1 = e;
    const float s2 = p[i0] + p[i1] + 1e-8f;
    const float w0 = p[i0] / s2, w1 = p[i1] / s2;
    gidx[2 * b] = i0; gidx[2 * b + 1] = i1;
    gwo[2 * b] = w0;  gwo[2 * b + 1] = w1;
    for (int e = 0; e < NEXP; e++)
      gated[b][e] = (e == i0) ? w0 : ((e == i1) ? w1 : 0.f);
  }
  __syncthreads();
  if (t == 0) {
    float imp[NEXP] = {0.f, 0.f, 0.f, 0.f};
    for (int b = 0; b < NBAT; b++)
      for (int e = 0; e < NEXP; e++) imp[e] += gated[b][e];
    float mean = 0.f;
    for (int e = 0; e < NEXP; e++) mean += imp[e];
    mean *= 0.25f;
    float var = 0.f;
    for (int e = 0; e < NEXP; e++) { const float d = imp[e] - mean; var += d * d; }
    var *= 0.25f;
    aux[0] = var / (mean * mean + 1e-10f);
  }
}

// ---------------- fused top-2 expert MLP ----------------
// v11: weights LDS-resident. R9/R10 proved the bottleneck is in-phase global
// weight/bias load latency (needs >128 regs of load-ILP), which is
// incompatible with >2 blocks/CU. So: eliminate globals from phases instead.
// 256 blocks x 512 thr (1 block/CU, 8 waves). Per block: stage BOTH experts'
// W2 (64 KB) into XOR-swizzled LDS once; hoist W1/W3/bias frags into regs
// (loop-invariant, (512,1) -> 256-reg budget, no cap pressure); then 16 tiles
// of 64 positions through L1/L2/L3 with pure LDS+MFMA phases.
// Wave map: L1/L2: wave w owns o-tile w (8x16=128). L3: ch=w>>1 (c-tile),
// nh2=w&1 (n-half). Xs double-buffered; next tile staged during s1.L2 phase.
// 4 barriers/tile. Swizzle: byte ^= (row&7)<<4, source pre-unswizzled (G21).
__global__ __launch_bounds__(512, 1)
void moe_main_k(const float* __restrict__ x, float* __restrict__ out,
                const _Float16* __restrict__ W1f, const _Float16* __restrict__ W2f,
                const _Float16* __restrict__ W3f,
                const float* __restrict__ b1f, const float* __restrict__ b2f,
                const float* __restrict__ b3f,
                const int* __restrict__ gidx, const float* __restrict__ gwv)
{
  // [0,65536): W2L both slots (swizzled, slot*32768, rows 256B)
  // [65536,81920): H1 [64n][128o] h16 swizzled
  // [81920,98304): H2
  // [98304,114688): Xs[2] [64n][64c] h16 swizzled
  __shared__ __align__(16) char smem[114688];

  const int bx  = blockIdx.x;
  const int b   = bx >> 4;            // sample
  const int n00 = (bx & 15) << 10;    // 1024-position chunk base
  const int t = threadIdx.x;
  const int w = t >> 6;               // wave 0..7
  const int lane = t & 63;
  const int ln = lane & 15, q = lane >> 4;
  const int ch = w >> 1, nh2 = w & 1; // L3 mapping

  const int   ea0 = gidx[2 * b],  ea1 = gidx[2 * b + 1];
  const float wa0 = gwv[2 * b],   wa1 = gwv[2 * b + 1];

  // ---- stage W2 for BOTH experts into swizzled LDS (8 x 16B per thread)
  // LDS linear (row, c') holds W2[row][c' ^ ((row&7)<<4)] (byte offsets).
#pragma unroll
  for (int i = 0; i < 8; i++) {
    const int D    = i * 8192 + t * 16;       // dest byte 0..65535
    const int row  = D >> 8;                  // 0..255 (e0:0-127, e1:128-255)
    const int colp = D & 255;
    const int col  = colp ^ ((row & 7) << 4);
    const int e    = (row & 128) ? ea1 : ea0;
    const f4 v = *(const f4*)(W2f + e * (HIDd * HIDd) + (row & 127) * HIDd + (col >> 1));
    *(f4*)(smem + D) = v;
  }

  // ---- hoisted per-slot fragments (loop-invariant; ~72 regs)
  h8 A1s[2][2], A3s[2][4];
  f4 bv1[2], bv2[2], bv3[2];
#pragma unroll
  for (int sl = 0; sl < 2; sl++) {
    const int e = sl ? ea1 : ea0;
    const _Float16* w1 = W1f + e * (HIDd * Cdim);
    A1s[sl][0] = *(const h8*)(w1 + (w * 16 + ln) * Cdim + q * 8);
    A1s[sl][1] = *(const h8*)(w1 + (w * 16 + ln) * Cdim + 32 + q * 8);
    const _Float16* w3 = W3f + e * (Cdim * HIDd);
#pragma unroll
    for (int ks = 0; ks < 4; ks++)
      A3s[sl][ks] = *(const h8*)(w3 + (ch * 16 + ln) * HIDd + ks * 32 + q * 8);
    bv1[sl] = *(const f4*)(b1f + e * HIDd + w * 16 + q * 4);
    bv2[sl] = *(const f4*)(b2f + e * HIDd + w * 16 + q * 4);
    bv3[sl] = *(const f4*)(b3f + e * Cdim + ch * 16 + q * 4);
  }

  f4 oacc[2];

  // ---- X tile staging: lane=position (coalesced 256B), 2 swizzled h4 writes
  auto stageX = [&](int buf, int tl) {
    char* XsB = smem + 98304 + buf * 8192;
    const int pos = lane;
    const int c0 = w << 3;              // wave w stages channels c0..c0+7
    const float* xp = x + ((size_t)b * Cdim + c0) * HWsz + n00 + tl * 64 + pos;
    float v[8];
#pragma unroll
    for (int j = 0; j < 8; j++) v[j] = xp[(size_t)j * HWsz];
    h4 p0, p1;
#pragma unroll
    for (int j = 0; j < 4; j++) { p0[j] = (_Float16)v[j]; p1[j] = (_Float16)v[4 + j]; }
    const int sw = (pos & 7) << 4;
    *(h4*)(XsB + pos * 128 + ((c0 * 2) ^ sw)) = p0;
    *(h4*)(XsB + pos * 128 + ((c0 * 2 + 8) ^ sw)) = p1;
  };

  // ---- L1: Xs -> H1 (wave w: o-tile w; 4 n-tiles x K=64)
  auto L1 = [&](int sl, int buf) {
    const char* XsB = smem + 98304 + buf * 8192;
    char* H1p = smem + 65536;
    __builtin_amdgcn_s_setprio(1);
#pragma unroll
    for (int nt = 0; nt < 4; nt++) {
      const int nrow = nt * 16 + ln;
      const int sw = (nrow & 7) << 4;
      const h8 bf0 = *(const h8*)(XsB + nrow * 128 + ((q * 16) ^ sw));
      const h8 bf1 = *(const h8*)(XsB + nrow * 128 + ((64 + q * 16) ^ sw));
      f4 acc = {0.f, 0.f, 0.f, 0.f};
      acc = __builtin_amdgcn_mfma_f32_16x16x32_f16(A1s[sl][0], bf0, acc, 0, 0, 0);
      acc = __builtin_amdgcn_mfma_f32_16x16x32_f16(A1s[sl][1], bf1, acc, 0, 0, 0);
      h4 hv;
#pragma unroll
      for (int r = 0; r < 4; r++) hv[r] = (_Float16)fmaxf(acc[r] + bv1[sl][r], 0.f);
      *(h4*)(H1p + nrow * 256 + (((w * 32) + (q * 8)) ^ sw)) = hv;
    }
    __builtin_amdgcn_s_setprio(0);
  };

  // ---- L2: H1 -> H2 (wave w: o-tile w; K=128, A from LDS W2L)
  auto L2 = [&](int sl) {
    const char* W2p = smem + sl * 32768;
    const char* H1p = smem + 65536;
    char* H2p = smem + 81920;
    const int arow = w * 16 + ln;
    const int asw = (ln & 7) << 4;       // (arow&7) == (ln&7)
    h8 a[4];
#pragma unroll
    for (int ks = 0; ks < 4; ks++)
      a[ks] = *(const h8*)(W2p + arow * 256 + ((ks * 64 + q * 16) ^ asw));
    __builtin_amdgcn_s_setprio(1);
#pragma unroll
    for (int nt = 0; nt < 4; nt++) {
      const int nrow = nt * 16 + ln;
      const int sw = (nrow & 7) << 4;
      h8 bf[4];
#pragma unroll
      for (int ks = 0; ks < 4; ks++)
        bf[ks] = *(const h8*)(H1p + nrow * 256 + ((ks * 64 + q * 16) ^ sw));
      f4 acc = {0.f, 0.f, 0.f, 0.f};
#pragma unroll
      for (int ks = 0; ks < 4; ks++)
        acc = __builtin_amdgcn_mfma_f32_16x16x32_f16(a[ks], bf[ks], acc, 0, 0, 0);
      h4 hv;
#pragma unroll
      for (int r = 0; r < 4; r++) hv[r] = (_Float16)fmaxf(acc[r] + bv2[sl][r], 0.f);
      *(h4*)(H2p + nrow * 256 + (((w * 32) + (q * 8)) ^ sw)) = hv;
    }
    __builtin_amdgcn_s_setprio(0);
  };

  // ---- L3: H2 -> oacc (wave w: c-tile ch, n-half nh2; K=128, weighted)
  auto L3 = [&](int sl) {
    const char* H2p = smem + 81920;
    const float we = sl ? wa1 : wa0;
    __builtin_amdgcn_s_setprio(1);
#pragma unroll
    for (int n2 = 0; n2 < 2; n2++) {
      const int nrow = (nh2 * 2 + n2) * 16 + ln;
      const int sw = (nrow & 7) << 4;
      h8 bf[4];
#pragma unroll
      for (int ks = 0; ks < 4; ks++)
        bf[ks] = *(const h8*)(H2p + nrow * 256 + ((ks * 64 + q * 16) ^ sw));
      f4 acc = {0.f, 0.f, 0.f, 0.f};
#pragma unroll
      for (int ks = 0; ks < 4; ks++)
        acc = __builtin_amdgcn_mfma_f32_16x16x32_f16(A3s[sl][ks], bf[ks], acc, 0, 0, 0);
#pragma unroll
      for (int r = 0; r < 4; r++) oacc[n2][r] += we * (acc[r] + bv3[sl][r]);
    }
    __builtin_amdgcn_s_setprio(0);
  };

  stageX(0, 0);
  __syncthreads();   // W2L + Xs[0] staged
  int cur = 0;

#pragma unroll 1
  for (int tl = 0; tl < 16; tl++) {
    oacc[0] = f4{0.f, 0.f, 0.f, 0.f};
    oacc[1] = f4{0.f, 0.f, 0.f, 0.f};

    L1(0, cur);                 // P1: X -> H1 (slot0)
    __syncthreads();
    L2(0);                      // P2: H1 -> H2 (slot0)
    __syncthreads();
    L3(0); L1(1, cur);          // P3: H2 -> oacc || X -> H1 (slot1; H1 free)
    __syncthreads();
    L2(1);                      // P4: H1 -> H2 (slot1; H2 free: P3 read done)
    if (tl < 15) stageX(cur ^ 1, tl + 1);   // next X into other buffer
    __syncthreads();
    L3(1);                      // P5: H2 -> oacc (slot1)

    // store this tile (fp32, nontemporal streaming)
#pragma unroll
    for (int n2 = 0; n2 < 2; n2++) {
      const int n = n00 + tl * 64 + (nh2 * 2 + n2) * 16 + ln;
#pragma unroll
      for (int r = 0; r < 4; r++)
        __builtin_nontemporal_store(oacc[n2][r],
            &out[((size_t)(b * Cdim + ch * 16 + q * 4 + r)) * HWsz + n]);
    }
    // no tile-end barrier needed: next L1 writes H1 (last read P4, bar'd) and
    // reads Xs[cur^1] (staged P4, bar'd); next L2 is gated by its own post-P1
    // barrier, after which all waves have finished P5's H2 reads.
    cur ^= 1;
  }
}

extern "C" void kernel_launch(void* const* d_in, const int* in_sizes, int n_in,
                              void* d_out, int out_size, void* d_ws, size_t ws_size,
                              hipStream_t stream)
{
  const float* x   = (const float*)d_in[0];
  const float* W1  = (const float*)d_in[1];
  const float* b1  = (const float*)d_in[2];
  const float* g1  = (const float*)d_in[3];
  const float* be1 = (const float*)d_in[4];
  const float* m1  = (const float*)d_in[5];
  const float* v1  = (const float*)d_in[6];
  const float* W2  = (const float*)d_in[7];
  const float* b2  = (const float*)d_in[8];
  const float* g2  = (const float*)d_in[9];
  const float* be2 = (const float*)d_in[10];
  const float* m2  = (const float*)d_in[11];
  const float* v2  = (const float*)d_in[12];
  const float* W3  = (const float*)d_in[13];
  const float* b3  = (const float*)d_in[14];
  const float* gwt = (const float*)d_in[15];
  const float* gb  = (const float*)d_in[16];

  char* ws = (char*)d_ws;
  _Float16* W1f = (_Float16*)(ws + OFF_W1F);
  _Float16* W2f = (_Float16*)(ws + OFF_W2F);
  _Float16* W3f = (_Float16*)(ws + OFF_W3F);
  float* b1f = (float*)(ws + OFF_B1F);
  float* b2f = (float*)(ws + OFF_B2F);
  float* b3f = (float*)(ws + OFF_B3F);
  float* gap = (float*)(ws + OFF_GAP);
  int*   gidx = (int*)(ws + OFF_GIDX);
  float* gwo = (float*)(ws + OFF_GW);

  float* out = (float*)d_out;
  float* aux = out + (size_t)NBAT * Cdim * HWsz;  // d_out[16777216]

  hipLaunchKernelGGL(prep_k, dim3(1542), dim3(256), 0, stream,
                     x, gap, W1, b1, g1, be1, m1, v1, W2, b2, g2, be2, m2, v2,
                     W3, b3, W1f, W2f, W3f, b1f, b2f, b3f);
  hipLaunchKernelGGL(gate_k, dim3(1), dim3(64), 0, stream, gap, gwt, gb, gidx, gwo, aux);
  hipLaunchKernelGGL(moe_main_k, dim3(256), dim3(512), 0, stream,
                     x, out, W1f, W2f, W3f, b1f, b2f, b3f, gidx, gwo);
}